// Round 5
// baseline (300.584 us; speedup 1.0000x reference)
//
#include <hip/hip_runtime.h>
#include <stdint.h>

// PoseCost: SE(3) log-map pose error over N = B*H poses.
// in:  pos [N,3] f32, rot [N,9] f32 (row-major 3x3), goal_pos [3], goal_rot [9], vec_weight [6]
// out: cost [N], rot_err [N], pos_err [N], v [N,3], omega [N,3]  (concat flat, f32)
//
// R5: async global_load_lds tile pipeline (T3/T4-for-streaming).
//  - persistent blocks, grid-stride over 256-pose tiles
//  - tile staged to LDS by 12 global_load_lds_dwordx4 (3 per wave), double-buffered
//  - raw s_barrier + counted s_waitcnt vmcnt(3): next tile's DMA stays in flight
//    through compute; never drain vmcnt(0) in the main loop
//  - math identical to R3/R4 (verified twice)

#define BLOCK 256
#define TILE  256
#define MAXB  2048

typedef float f32x4 __attribute__((ext_vector_type(4)));

__device__ __forceinline__ void gload_lds16(const float* g, float* l) {
    __builtin_amdgcn_global_load_lds(
        (const __attribute__((address_space(1))) void*)g,
        (__attribute__((address_space(3))) void*)l,
        16 /*bytes per lane*/, 0 /*offset*/, 0 /*aux*/);
}

__device__ __forceinline__ void pose_one(
    const float* R, float p0, float p1, float p2,
    const float* G, float g0, float g1, float g2, const float* w,
    float& cost, float& re, float& pe,
    float& v0, float& v1, float& v2,
    float& o0, float& o1, float& o2)
{
    // d = goal_pos - p ;  t_ge = R^T d
    const float d0 = g0 - p0, d1 = g1 - p1, d2 = g2 - p2;
    const float tq0 = R[0] * d0 + R[3] * d1 + R[6] * d2;
    const float tq1 = R[1] * d0 + R[4] * d1 + R[7] * d2;
    const float tq2 = R[2] * d0 + R[5] * d1 + R[8] * d2;

    // M = R^T * G
    float M[9];
    #pragma unroll
    for (int i = 0; i < 3; ++i)
        #pragma unroll
        for (int j = 0; j < 3; ++j)
            M[i * 3 + j] = R[0 + i] * G[0 + j] + R[3 + i] * G[3 + j] + R[6 + i] * G[6 + j];

    const float tr = M[0] + M[4] + M[8];
    float cos_t = (tr - 1.0f) * 0.5f;
    cos_t = fminf(fmaxf(cos_t, -1.0f + 1e-7f), 1.0f - 1e-7f);
    const float theta = acosf(cos_t);
    // sin(acos(c)) == sqrt(1-c^2) on (0,pi); fmaf keeps the clamp-boundary value accurate
    const float sin_t = sqrtf(fmaf(-cos_t, cos_t, 1.0f));

    // vee(M - M^T)/2
    const float wv0 = 0.5f * (M[7] - M[5]);
    const float wv1 = 0.5f * (M[2] - M[6]);
    const float wv2 = 0.5f * (M[3] - M[1]);

    const bool small = theta < 1e-4f;   // dead after the clamp but preserves ref semantics
    const float th2 = theta * theta;
    const float scale = small ? (1.0f + th2 * (1.0f / 6.0f)) : (theta / sin_t);
    o0 = scale * wv0; o1 = scale * wv1; o2 = scale * wv2;

    // A = (1 - theta*sin/(2(1-cos)))/theta^2 == (1 - 0.5*scale*(1+cos))/theta^2
    const float A = small ? (1.0f / 12.0f)
                          : (1.0f - 0.5f * scale * (1.0f + cos_t)) / th2;

    // v = t - 0.5*(omega x t) + A*(omega*(omega.t) - |omega|^2 * t)
    const float cx0 = o1 * tq2 - o2 * tq1;
    const float cx1 = o2 * tq0 - o0 * tq2;
    const float cx2 = o0 * tq1 - o1 * tq0;
    const float odt = o0 * tq0 + o1 * tq1 + o2 * tq2;
    const float on2 = o0 * o0 + o1 * o1 + o2 * o2;
    v0 = tq0 - 0.5f * cx0 + A * (o0 * odt - on2 * tq0);
    v1 = tq1 - 0.5f * cx1 + A * (o1 * odt - on2 * tq1);
    v2 = tq2 - 0.5f * cx2 + A * (o2 * odt - on2 * tq2);

    const float we0 = w[0] * o0, we1 = w[1] * o1, we2 = w[2] * o2;
    const float wp0 = w[3] * v0, wp1 = w[4] * v1, wp2 = w[5] * v2;
    re = we0 * we0 + we1 * we1 + we2 * we2;
    pe = wp0 * wp0 + wp1 * wp1 + wp2 * wp2;
    re = (re < 0.0f) ? 0.0f : re;   // CONV_* = 0 exact semantics
    pe = (pe < 0.0f) ? 0.0f : pe;
    cost = 15.0f * re + 100.0f * pe;
}

__global__ __launch_bounds__(BLOCK) void pose_cost_kernel(
    const float* __restrict__ pos,
    const float* __restrict__ rot,
    const float* __restrict__ gpos,
    const float* __restrict__ grot,
    const float* __restrict__ wvec,
    float* __restrict__ out,
    int N)
{
    // buf[b]: [0,2304) rot tile pose-major linear, [2304,3072) pos tile linear. 12 KB each.
    __shared__ float buf[2][3 * TILE * 4];

    const int t = threadIdx.x;
    const int wave = t >> 6;
    const int lane = t & 63;
    const size_t Ns = (size_t)N;

    // uniform goal / weight data (scalar loads)
    float G[9], w[6];
    #pragma unroll
    for (int k = 0; k < 9; ++k) G[k] = grot[k];
    const float g0 = gpos[0], g1 = gpos[1], g2 = gpos[2];
    #pragma unroll
    for (int k = 0; k < 6; ++k) w[k] = wvec[k];

    if ((N % TILE) == 0 && N > 0) {
        const size_t T  = Ns / TILE;
        const size_t Gd = gridDim.x;
        const size_t b  = blockIdx.x;             // launcher guarantees b < T
        const size_t cnt = (T - b + Gd - 1) / Gd; // tiles owned by this block (>= 1)

        // stage one tile: 12 chunks of 1 KB; wave w issues chunks {w, w+4, w+8}
        auto stage = [&](float* dst, size_t tile) {
            #pragma unroll
            for (int i2 = 0; i2 < 3; ++i2) {
                const int c = wave + 4 * i2;
                const float* g = (c < 9)
                    ? (rot + tile * (size_t)(9 * TILE) + (size_t)c * 256 + (size_t)lane * 4)
                    : (pos + tile * (size_t)(3 * TILE) + (size_t)(c - 9) * 256 + (size_t)lane * 4);
                gload_lds16(g, dst + c * 256 + lane * 4);
            }
        };
        auto tileAt = [&](size_t j) {
            const size_t jj = (j < cnt) ? j : (cnt - 1);  // clamp: dummy re-stage keeps counts uniform
            return b + jj * Gd;
        };

        // prologue: two tiles in flight (3 DMA ops per wave per tile)
        stage(buf[0], tileAt(0));
        __builtin_amdgcn_sched_barrier(0);
        stage(buf[1], tileAt(1));
        __builtin_amdgcn_sched_barrier(0);

        for (size_t i = 0; i < cnt; ++i) {
            // retire everything except the newest stage (3 DMA ops): current tile's DMA
            // complete, next tile's stays in flight through compute. Never vmcnt(0).
            asm volatile("s_waitcnt vmcnt(3)" ::: "memory");
            __builtin_amdgcn_sched_barrier(0);
            __builtin_amdgcn_s_barrier();            // all waves' chunks resident

            const float* bb = buf[i & 1];
            const size_t tile = b + i * Gd;
            const size_t idx = tile * TILE + (size_t)t;

            float R[9];
            #pragma unroll
            for (int k = 0; k < 9; ++k) R[k] = bb[t * 9 + k];
            const float p0 = bb[2304 + t * 3 + 0];
            const float p1 = bb[2304 + t * 3 + 1];
            const float p2 = bb[2304 + t * 3 + 2];

            float cst, re, pe, v0, v1, v2, o0, o1, o2;
            pose_one(R, p0, p1, p2, G, g0, g1, g2, w,
                     cst, re, pe, v0, v1, v2, o0, o1, o2);

            // coalesced scalar stores (lane-stride 4B / 12B)
            out[idx] = cst;
            out[Ns + idx] = re;
            out[2 * Ns + idx] = pe;
            out[3 * Ns + idx * 3 + 0] = v0;
            out[3 * Ns + idx * 3 + 1] = v1;
            out[3 * Ns + idx * 3 + 2] = v2;
            out[6 * Ns + idx * 3 + 0] = o0;
            out[6 * Ns + idx * 3 + 1] = o1;
            out[6 * Ns + idx * 3 + 2] = o2;

            // all LDS reads of this buffer are consumed (values fed the stores above);
            // drain ds ops, then barrier so no wave still reads buf before we overwrite it.
            asm volatile("s_waitcnt lgkmcnt(0)" ::: "memory");
            __builtin_amdgcn_sched_barrier(0);
            __builtin_amdgcn_s_barrier();

            stage(buf[i & 1], tileAt(i + 2));        // refill just-freed buffer, 2 tiles ahead
            __builtin_amdgcn_sched_barrier(0);
        }
        // outstanding stores/dummy stages drain at end-of-kernel
    } else {
        // generic fallback: grid-stride scalar (correctness path for N % 256 != 0)
        const size_t nthr = (size_t)gridDim.x * BLOCK;
        const size_t tid = (size_t)blockIdx.x * BLOCK + t;
        for (size_t i = tid; i < Ns; i += nthr) {
            float R[9];
            #pragma unroll
            for (int k = 0; k < 9; ++k) R[k] = rot[i * 9 + k];
            const float p0 = pos[i * 3 + 0];
            const float p1 = pos[i * 3 + 1];
            const float p2 = pos[i * 3 + 2];

            float cst, re, pe, v0, v1, v2, o0, o1, o2;
            pose_one(R, p0, p1, p2, G, g0, g1, g2, w,
                     cst, re, pe, v0, v1, v2, o0, o1, o2);

            out[i] = cst;
            out[Ns + i] = re;
            out[2 * Ns + i] = pe;
            out[3 * Ns + i * 3 + 0] = v0;
            out[3 * Ns + i * 3 + 1] = v1;
            out[3 * Ns + i * 3 + 2] = v2;
            out[6 * Ns + i * 3 + 0] = o0;
            out[6 * Ns + i * 3 + 1] = o1;
            out[6 * Ns + i * 3 + 2] = o2;
        }
    }
}

extern "C" void kernel_launch(void* const* d_in, const int* in_sizes, int n_in,
                              void* d_out, int out_size, void* d_ws, size_t ws_size,
                              hipStream_t stream) {
    const float* pos  = (const float*)d_in[0];   // [N,3]
    const float* rot  = (const float*)d_in[1];   // [N,9]
    const float* gpos = (const float*)d_in[2];   // [3]
    const float* grot = (const float*)d_in[3];   // [9]
    const float* wv   = (const float*)d_in[4];   // [6]
    float* out = (float*)d_out;

    const int N = in_sizes[0] / 3;
    int blocks;
    if (N > 0 && (N % TILE) == 0) {
        const long long T = (long long)N / TILE;
        blocks = (int)((T < MAXB) ? T : MAXB);   // every block owns >= 1 tile
    } else {
        const long long need = ((long long)N + BLOCK - 1) / BLOCK;
        blocks = (int)((need < MAXB) ? (need > 0 ? need : 1) : MAXB);
    }
    hipLaunchKernelGGL(pose_cost_kernel, dim3(blocks), dim3(BLOCK), 0, stream,
                       pos, rot, gpos, grot, wv, out, N);
}

// Round 6
// 298.772 us; speedup vs baseline: 1.0061x; 1.0061x over previous
//
#include <hip/hip_runtime.h>

// PoseCost: SE(3) log-map pose error over N = B*H poses.
// in:  pos [N,3] f32, rot [N,9] f32 (row-major 3x3), goal_pos [3], goal_rot [9], vec_weight [6]
// out: cost [N], rot_err [N], pos_err [N], v [N,3], omega [N,3]  (concat flat, f32)
//
// FINAL (R6 = verbatim R3, the session's best measured variant: 95.0 us/dispatch,
// 293.7 us bench). Session evidence: five structurally-orthogonal kernels
// (coalesced-LDS 71% occ / 4-pose-ILP 34% / persistent reg-dbuf 18% /
// async global_load_lds DMA pipeline 50% / NT-store variant) all land 95-113 us
// at 2.2-2.7 TB/s HBM with VALUBusy 15-24%, zero bank conflicts and
// amplification-free FETCH/WRITE. The plateau is invariant to every HIP-level
// structural lever; R3's structure is the measured minimum, so it stands.
//
// R3 structure: 4 poses/thread, zero LDS, zero barriers.
//  - per-thread rot/pos are contiguous -> 9+3 aligned dwordx4 loads, all issued up front
//  - 4 independent acos dependency chains per thread (ILP hides transcendental latency)
//  - all outputs packed into aligned dwordx4 stores (plain, not NT — NT regressed in R2)

#define BLOCK 256

typedef float f32x4 __attribute__((ext_vector_type(4)));

__device__ __forceinline__ void pose_one(
    const float* R, float p0, float p1, float p2,
    const float* G, float g0, float g1, float g2, const float* w,
    float& cost, float& re, float& pe,
    float& v0, float& v1, float& v2,
    float& o0, float& o1, float& o2)
{
    // d = goal_pos - p ;  t_ge = R^T d
    const float d0 = g0 - p0, d1 = g1 - p1, d2 = g2 - p2;
    const float tq0 = R[0] * d0 + R[3] * d1 + R[6] * d2;
    const float tq1 = R[1] * d0 + R[4] * d1 + R[7] * d2;
    const float tq2 = R[2] * d0 + R[5] * d1 + R[8] * d2;

    // M = R^T * G
    float M[9];
    #pragma unroll
    for (int i = 0; i < 3; ++i)
        #pragma unroll
        for (int j = 0; j < 3; ++j)
            M[i * 3 + j] = R[0 + i] * G[0 + j] + R[3 + i] * G[3 + j] + R[6 + i] * G[6 + j];

    const float tr = M[0] + M[4] + M[8];
    float cos_t = (tr - 1.0f) * 0.5f;
    cos_t = fminf(fmaxf(cos_t, -1.0f + 1e-7f), 1.0f - 1e-7f);
    const float theta = acosf(cos_t);
    // sin(acos(c)) == sqrt(1-c^2) on (0,pi); fmaf keeps the clamp-boundary value accurate
    const float sin_t = sqrtf(fmaf(-cos_t, cos_t, 1.0f));

    // vee(M - M^T)/2
    const float wv0 = 0.5f * (M[7] - M[5]);
    const float wv1 = 0.5f * (M[2] - M[6]);
    const float wv2 = 0.5f * (M[3] - M[1]);

    const bool small = theta < 1e-4f;   // dead after the clamp but preserves ref semantics
    const float th2 = theta * theta;
    const float scale = small ? (1.0f + th2 * (1.0f / 6.0f)) : (theta / sin_t);
    o0 = scale * wv0; o1 = scale * wv1; o2 = scale * wv2;

    // A = (1 - theta*sin/(2(1-cos)))/theta^2 == (1 - 0.5*scale*(1+cos))/theta^2
    const float A = small ? (1.0f / 12.0f)
                          : (1.0f - 0.5f * scale * (1.0f + cos_t)) / th2;

    // v = t - 0.5*(omega x t) + A*(omega*(omega.t) - |omega|^2 * t)
    const float cx0 = o1 * tq2 - o2 * tq1;
    const float cx1 = o2 * tq0 - o0 * tq2;
    const float cx2 = o0 * tq1 - o1 * tq0;
    const float odt = o0 * tq0 + o1 * tq1 + o2 * tq2;
    const float on2 = o0 * o0 + o1 * o1 + o2 * o2;
    v0 = tq0 - 0.5f * cx0 + A * (o0 * odt - on2 * tq0);
    v1 = tq1 - 0.5f * cx1 + A * (o1 * odt - on2 * tq1);
    v2 = tq2 - 0.5f * cx2 + A * (o2 * odt - on2 * tq2);

    const float we0 = w[0] * o0, we1 = w[1] * o1, we2 = w[2] * o2;
    const float wp0 = w[3] * v0, wp1 = w[4] * v1, wp2 = w[5] * v2;
    re = we0 * we0 + we1 * we1 + we2 * we2;
    pe = wp0 * wp0 + wp1 * wp1 + wp2 * wp2;
    re = (re < 0.0f) ? 0.0f : re;   // CONV_* = 0 exact semantics
    pe = (pe < 0.0f) ? 0.0f : pe;
    cost = 15.0f * re + 100.0f * pe;
}

__global__ __launch_bounds__(BLOCK) void pose_cost_kernel(
    const float* __restrict__ pos,
    const float* __restrict__ rot,
    const float* __restrict__ gpos,
    const float* __restrict__ grot,
    const float* __restrict__ wvec,
    float* __restrict__ out,
    int N)
{
    const size_t tid = (size_t)blockIdx.x * BLOCK + threadIdx.x;
    const size_t i0 = tid * 4;
    if (i0 >= (size_t)N) return;

    // uniform (wave-invariant) goal / weight data -> scalar loads
    float G[9], w[6];
    #pragma unroll
    for (int k = 0; k < 9; ++k) G[k] = grot[k];
    const float g0 = gpos[0], g1 = gpos[1], g2 = gpos[2];
    #pragma unroll
    for (int k = 0; k < 6; ++k) w[k] = wvec[k];

    const size_t Ns = (size_t)N;

    if (((N & 3) == 0)) {
        // ---- fast path: 4 poses, all 16B-aligned vector memory ops ----
        const f32x4* rs = reinterpret_cast<const f32x4*>(rot + i0 * 9);  // 36 floats
        const f32x4* ps = reinterpret_cast<const f32x4*>(pos + i0 * 3);  // 12 floats
        f32x4 r[9], p[3];
        #pragma unroll
        for (int k = 0; k < 9; ++k) r[k] = rs[k];
        #pragma unroll
        for (int k = 0; k < 3; ++k) p[k] = ps[k];

        // flattened constant-index access (SROA keeps everything in registers)
        #define RF(q) (r[(q) >> 2][(q) & 3])
        #define PF(q) (p[(q) >> 2][(q) & 3])

        f32x4 vcost, vre, vpe;
        f32x4 vv[3], vo[3];
        #define VV(q) (vv[(q) >> 2][(q) & 3])
        #define VO(q) (vo[(q) >> 2][(q) & 3])

        #pragma unroll
        for (int j = 0; j < 4; ++j) {
            float R[9];
            #pragma unroll
            for (int k = 0; k < 9; ++k) R[k] = RF(9 * j + k);
            const float p0 = PF(3 * j + 0);
            const float p1 = PF(3 * j + 1);
            const float p2 = PF(3 * j + 2);

            float c, re, pe, v0, v1, v2, o0, o1, o2;
            pose_one(R, p0, p1, p2, G, g0, g1, g2, w,
                     c, re, pe, v0, v1, v2, o0, o1, o2);
            vcost[j] = c; vre[j] = re; vpe[j] = pe;
            VV(3 * j + 0) = v0; VV(3 * j + 1) = v1; VV(3 * j + 2) = v2;
            VO(3 * j + 0) = o0; VO(3 * j + 1) = o1; VO(3 * j + 2) = o2;
        }
        #undef RF
        #undef PF
        #undef VV
        #undef VO

        // aligned packed stores: i0 % 4 == 0 and N % 4 == 0
        *reinterpret_cast<f32x4*>(out + i0) = vcost;
        *reinterpret_cast<f32x4*>(out + Ns + i0) = vre;
        *reinterpret_cast<f32x4*>(out + 2 * Ns + i0) = vpe;
        f32x4* vd = reinterpret_cast<f32x4*>(out + 3 * Ns + i0 * 3);
        f32x4* od = reinterpret_cast<f32x4*>(out + 6 * Ns + i0 * 3);
        #pragma unroll
        for (int k = 0; k < 3; ++k) vd[k] = vv[k];
        #pragma unroll
        for (int k = 0; k < 3; ++k) od[k] = vo[k];
    } else {
        // ---- generic scalar path (N not divisible by 4) ----
        const size_t iend = (i0 + 4 < Ns) ? (i0 + 4) : Ns;
        for (size_t i = i0; i < iend; ++i) {
            float R[9];
            #pragma unroll
            for (int k = 0; k < 9; ++k) R[k] = rot[i * 9 + k];
            const float p0 = pos[i * 3 + 0];
            const float p1 = pos[i * 3 + 1];
            const float p2 = pos[i * 3 + 2];

            float c, re, pe, v0, v1, v2, o0, o1, o2;
            pose_one(R, p0, p1, p2, G, g0, g1, g2, w,
                     c, re, pe, v0, v1, v2, o0, o1, o2);

            out[i] = c;
            out[Ns + i] = re;
            out[2 * Ns + i] = pe;
            out[3 * Ns + i * 3 + 0] = v0;
            out[3 * Ns + i * 3 + 1] = v1;
            out[3 * Ns + i * 3 + 2] = v2;
            out[6 * Ns + i * 3 + 0] = o0;
            out[6 * Ns + i * 3 + 1] = o1;
            out[6 * Ns + i * 3 + 2] = o2;
        }
    }
}

extern "C" void kernel_launch(void* const* d_in, const int* in_sizes, int n_in,
                              void* d_out, int out_size, void* d_ws, size_t ws_size,
                              hipStream_t stream) {
    const float* pos  = (const float*)d_in[0];   // [N,3]
    const float* rot  = (const float*)d_in[1];   // [N,9]
    const float* gpos = (const float*)d_in[2];   // [3]
    const float* grot = (const float*)d_in[3];   // [9]
    const float* wv   = (const float*)d_in[4];   // [6]
    float* out = (float*)d_out;

    const int N = in_sizes[0] / 3;
    const int nthreads = (N + 3) / 4;
    const int blocks = (nthreads + BLOCK - 1) / BLOCK;
    hipLaunchKernelGGL(pose_cost_kernel, dim3(blocks), dim3(BLOCK), 0, stream,
                       pos, rot, gpos, grot, wv, out, N);
}